// Round 1
// 298.087 us; speedup vs baseline: 1.0146x; 1.0146x over previous
//
#include <hip/hip_runtime.h>
#include <cstdint>
#include <cstddef>

// Problem constants
#define SS    2304            // 48*48
#define OUT0  4718592         // 8*256*48*48
// probs region: 47,775,744 floats after OUT0

typedef short bf16x8 __attribute__((ext_vector_type(8)));
typedef float f32x4  __attribute__((ext_vector_type(4)));

__device__ __forceinline__ unsigned short f2bf(float f) {
    union { float f; unsigned int i; } v; v.f = f;
    unsigned int x = v.i;
    unsigned int r = x + 0x7fffu + ((x >> 16) & 1u);   // RNE
    return (unsigned short)(r >> 16);
}

__device__ __forceinline__ unsigned int pack2(float a, float b) {
    return (unsigned int)f2bf(a) | ((unsigned int)f2bf(b) << 16);
}

// ---------------------------------------------------------------------------
// K1 (combined front): blocks 0..107 softmax init (4 rows/block);
// blocks 108..395 Wv fp32 [e][k] -> WF bf16 [kb][e][kk] pack;
// blocks 396..1547 hs fp32 -> XB bf16 pre-convert (16 floats/thread).
// All roles LDS-free -> high occupancy, mutually overlapped.  Moving the
// Wv-pack here (out of k_attn) removes 288 no-LDS blocks from the
// 36.9-KB-LDS kernel (R10 lesson applied to pack, not just probs).
// ---------------------------------------------------------------------------
__global__ __launch_bounds__(256) void k_pre(const float* __restrict__ centers,
                                             const float* __restrict__ spreads,
                                             const float* __restrict__ hs,
                                             const float* __restrict__ Wv,
                                             float* __restrict__ p1, float* __restrict__ p2,
                                             unsigned short* __restrict__ p1b,
                                             unsigned short* __restrict__ p2b,
                                             unsigned short* __restrict__ XB,
                                             unsigned short* __restrict__ WF) {
    int blk = blockIdx.x;
    int t = threadIdx.x;

    if (blk < 108) {                        // ---- softmax init ----
        int lane = t & 63, wave = t >> 6;
        int ridx = blk * 4 + wave;          // 0..431
        int h = ridx / 48, r = ridx % 48;
        float a = spreads[h]; a = a * a;
        float mu1 = centers[2 * h + 0];
        float mu2 = centers[2 * h + 1];
        bool act = lane < 48;
        float dx = (float)(lane - r);
        float q  = -0.5f * a * dx * dx;
        float g1 = act ? (a * mu1 * dx + q) : -INFINITY;
        float g2 = act ? (a * mu2 * dx + q) : -INFINITY;
        float m1 = g1, m2 = g2;
        #pragma unroll
        for (int off = 32; off >= 1; off >>= 1) {
            m1 = fmaxf(m1, __shfl_xor(m1, off));
            m2 = fmaxf(m2, __shfl_xor(m2, off));
        }
        float e1 = act ? expf(g1 - m1) : 0.f;
        float e2 = act ? expf(g2 - m2) : 0.f;
        float s1 = e1, s2 = e2;
        #pragma unroll
        for (int off = 32; off >= 1; off >>= 1) {
            s1 += __shfl_xor(s1, off);
            s2 += __shfl_xor(s2, off);
        }
        float v1 = e1 / s1, v2 = e2 / s2;
        if (act) {
            p1[h * SS + r * 48 + lane] = v1;
            p2[h * SS + r * 48 + lane] = v2;
        }
        p1b[(h * 48 + r) * 64 + lane] = act ? f2bf(v1) : 0;
        p2b[(h * 48 + r) * 64 + lane] = act ? f2bf(v2) : 0;
        return;
    }

    if (blk < 396) {                        // ---- Wv pack unit ----
        int kb = blk - 108;                 // 0..287
        const float* src = Wv + (size_t)t * 2304 + kb * 8;
        float4 f0 = *(const float4*)src;
        float4 f1 = *(const float4*)(src + 4);
        uint4 o;
        o.x = pack2(f0.x, f0.y);
        o.y = pack2(f0.z, f0.w);
        o.z = pack2(f1.x, f1.y);
        o.w = pack2(f1.z, f1.w);
        *(uint4*)(WF + ((size_t)kb * 256 + t) * 8) = o;
        return;
    }

    // ---- hs fp32 -> XB bf16 (same RNE as before => bit-identical math) ----
    size_t base = ((size_t)(blk - 396) * 256 + t) * 16;   // 1152*256*16 = 4,718,592
    const float4* s4 = (const float4*)(hs + base);
    float4 f0 = s4[0], f1 = s4[1], f2 = s4[2], f3 = s4[3];
    uint4 o0, o1;
    o0.x = pack2(f0.x, f0.y); o0.y = pack2(f0.z, f0.w);
    o0.z = pack2(f1.x, f1.y); o0.w = pack2(f1.z, f1.w);
    o1.x = pack2(f2.x, f2.y); o1.y = pack2(f2.z, f2.w);
    o1.z = pack2(f3.x, f3.y); o1.w = pack2(f3.z, f3.w);
    *(uint4*)(XB + base)     = o0;
    *(uint4*)(XB + base + 8) = o1;
}

// ---------------------------------------------------------------------------
// K2 (attention apply): 2304 blocks, per (h, b, d-octet): S^T = X*p1^T
// (mfma1, swapped operands), V^T = S*p2^T (mfma2).
// Changes this round:
//  * X fragments come from pre-converted bf16 XB (16-B direct loads, no f2bf,
//    half the staging bytes) and are hoisted for BOTH s-passes up front so
//    s=1's global latency hides under s=0's compute.
//  * S-LDS XOR swizzle (col ^= (row&7)<<4 on the byte offset, pitch 160 B)
//    applied consistently to pad-write / spill-write / a2f-read: the b128
//    read drops from 8-way bank conflict (~2.94x, m136) to <=2-way (free).
//  * Wv-pack blocks moved out to k_pre (no no-LDS workers in this kernel).
// NOTE (R10 lesson): do NOT put no-LDS worker blocks in this kernel — the
// static 36.9 KB LDS allocation applies to every block regardless of branch.
// ---------------------------------------------------------------------------
__global__ __launch_bounds__(256, 3) void k_attn(const unsigned short* __restrict__ XB,
                                                 const unsigned short* __restrict__ p1b,
                                                 const unsigned short* __restrict__ p2b,
                                                 unsigned short* __restrict__ AF) {
    __shared__ unsigned short LSH[18432];   // 36864 B: S phase then Vbuf phase

    int blk = blockIdx.x;
    int t = threadIdx.x;

    int h = blk >> 8;
    int rem = blk & 255;
    int b = rem >> 5, od = rem & 31;
    int d0 = od * 8;
    int kb = h * 32 + od;

    int lane = t & 63, wave = t >> 6;
    int l15 = lane & 15, quad = lane >> 4;

    // Preload p1 / p2 frags (A/B layouts symmetric for 16x16x32)
    const bf16x8* P1 = (const bf16x8*)(p1b + (size_t)h * 3072);
    const bf16x8* P2 = (const bf16x8*)(p2b + (size_t)h * 3072);
    bf16x8 pa[3][2], pb[3][2];
    #pragma unroll
    for (int tt = 0; tt < 3; ++tt)
        #pragma unroll
        for (int kt = 0; kt < 2; ++kt) {
            int u = (tt * 16 + l15) * 8 + kt * 4 + quad;
            pa[tt][kt] = P1[u];
            pb[tt][kt] = P2[u];
        }

    // X frags for BOTH s-passes, straight from bf16 XB; k>=48 zero.
    // Hoisted before any LDS work so the loads pipeline under pass 0.
    bf16x8 bxs[2][3][2];
    #pragma unroll
    for (int s = 0; s < 2; ++s) {
        int d = d0 + wave * 2 + s;
        const unsigned short* X = XB + ((size_t)b * 256 + d) * SS;
        #pragma unroll
        for (int lt = 0; lt < 3; ++lt)
            #pragma unroll
            for (int kt = 0; kt < 2; ++kt) {
                bf16x8 v = __builtin_bit_cast(bf16x8, (uint4){0u, 0u, 0u, 0u});
                if (kt == 0 || quad < 2)
                    v = *(const bf16x8*)(X + (lt * 16 + l15) * 48 + kt * 32 + quad * 8);
                bxs[s][lt][kt] = v;
            }
    }

    // Phase 1: S-LDS = wave-private [i][l], pitch 160 B, XOR-swizzled cols
    unsigned char* Swb = (unsigned char*)LSH + wave * 7680;
    // zero pad: logical col bytes 96..127 (l = 48..63)
    for (int z = lane; z < 384; z += 64) {
        int row = z >> 3;
        int col = 96 + ((z & 7) << 2);
        *(unsigned int*)(Swb + row * 160 + (col ^ ((row & 7) << 4))) = 0u;
    }

    f32x4 a2k[2][9];        // V^T accs for both s-passes (held across phase 2)

    #pragma unroll
    for (int s = 0; s < 2; ++s) {
        // mfma1 (SWAPPED operands): D = S^T, rows = l, cols = i
        f32x4 a1[9];
        #pragma unroll
        for (int q = 0; q < 9; ++q) a1[q] = (f32x4){0.f, 0.f, 0.f, 0.f};
        #pragma unroll
        for (int lt = 0; lt < 3; ++lt)
            #pragma unroll
            for (int it = 0; it < 3; ++it) {
                a1[lt * 3 + it] = __builtin_amdgcn_mfma_f32_16x16x32_bf16(
                    bxs[s][lt][0], pa[it][0], a1[lt * 3 + it], 0, 0, 0);
                a1[lt * 3 + it] = __builtin_amdgcn_mfma_f32_16x16x32_bf16(
                    bxs[s][lt][1], pa[it][1], a1[lt * 3 + it], 0, 0, 0);
            }

        // S^T tile -> S[i][l] LDS: lane holds i = it*16+l15 (col), l = lt*16+quad*4+reg
        // one packed 8B write per tile, XOR-swizzled
        #pragma unroll
        for (int lt = 0; lt < 3; ++lt)
            #pragma unroll
            for (int it = 0; it < 3; ++it) {
                f32x4 v = a1[lt * 3 + it];
                uint2 u2;
                u2.x = pack2(v[0], v[1]);
                u2.y = pack2(v[2], v[3]);
                int row = it * 16 + l15;
                int col = lt * 32 + quad * 8;        // bytes = (lt*16+quad*4)*2
                *(uint2*)(Swb + row * 160 + (col ^ ((row & 7) << 4))) = u2;
            }

        // A2-frags: lane holds S[i = it*16+l15][kt*32+quad*8 ..+7], XOR-swizzled read
        bf16x8 a2f[3][2];
        #pragma unroll
        for (int it = 0; it < 3; ++it)
            #pragma unroll
            for (int kt = 0; kt < 2; ++kt) {
                int row = it * 16 + l15;
                int col = kt * 64 + quad * 16;
                a2f[it][kt] = *(const bf16x8*)(Swb + row * 160 + (col ^ ((row & 7) << 4)));
            }

        // mfma2: V^T[i,j] -> a2k[s]
        #pragma unroll
        for (int q = 0; q < 9; ++q) a2k[s][q] = (f32x4){0.f, 0.f, 0.f, 0.f};
        #pragma unroll
        for (int it = 0; it < 3; ++it)
            #pragma unroll
            for (int jt = 0; jt < 3; ++jt) {
                a2k[s][it * 3 + jt] = __builtin_amdgcn_mfma_f32_16x16x32_bf16(
                    a2f[it][0], pb[jt][0], a2k[s][it * 3 + jt], 0, 0, 0);
                a2k[s][it * 3 + jt] = __builtin_amdgcn_mfma_f32_16x16x32_bf16(
                    a2f[it][1], pb[jt][1], a2k[s][it * 3 + jt], 0, 0, 0);
            }
    }

    // Phase 2: Vbuf = LSH as [kk][2304] (aliases S-LDS; S fully consumed)
    __syncthreads();
    #pragma unroll
    for (int s = 0; s < 2; ++s) {
        int kk = wave * 2 + s;
        #pragma unroll
        for (int it = 0; it < 3; ++it)
            #pragma unroll
            for (int jt = 0; jt < 3; ++jt) {
                f32x4 v = a2k[s][it * 3 + jt];
                uint2 u2;
                u2.x = pack2(v[0], v[1]);
                u2.y = pack2(v[2], v[3]);
                int m = (jt * 16 + l15) * 48 + it * 16 + quad * 4;
                *(uint2*)(LSH + kk * 2304 + m) = u2;
            }
    }
    __syncthreads();

    // Epilogue: AF[b][kb][m][kk] <- Vbuf[kk][m], full-16B uint4 stores
    const uint2* Vr = (const uint2*)LSH;     // 576 uint2 per kk row
    uint4* AFq = (uint4*)AF;
    size_t abase = (size_t)(b * 288 + kb) * 2304;
    for (int g = t; g < 576; g += 256) {
        uint2 rk[8];
        #pragma unroll
        for (int kk = 0; kk < 8; ++kk) rk[kk] = Vr[kk * 576 + g];
        #pragma unroll
        for (int mi = 0; mi < 4; ++mi) {
            unsigned int sel = (mi & 1) ? 0x07060302u : 0x05040100u;
            uint4 o;
            if (mi < 2) {
                o.x = __builtin_amdgcn_perm(rk[1].x, rk[0].x, sel);
                o.y = __builtin_amdgcn_perm(rk[3].x, rk[2].x, sel);
                o.z = __builtin_amdgcn_perm(rk[5].x, rk[4].x, sel);
                o.w = __builtin_amdgcn_perm(rk[7].x, rk[6].x, sel);
            } else {
                o.x = __builtin_amdgcn_perm(rk[1].y, rk[0].y, sel);
                o.y = __builtin_amdgcn_perm(rk[3].y, rk[2].y, sel);
                o.z = __builtin_amdgcn_perm(rk[5].y, rk[4].y, sel);
                o.w = __builtin_amdgcn_perm(rk[7].y, rk[6].y, sel);
            }
            AFq[abase + g * 4 + mi] = o;
        }
    }
}

// ---------------------------------------------------------------------------
// probs unit: 8 (i,j,h) tiles; probs[idx][k*48+l] = p1[h,i,k]*p2[h,j,l]
// no LDS, nontemporal float4 stores
// ---------------------------------------------------------------------------
__device__ __forceinline__ void probs_unit(int u, int t,
                                           const float* __restrict__ p1,
                                           const float* __restrict__ p2,
                                           float* __restrict__ probs) {
    #pragma unroll 2
    for (int tt = 0; tt < 8; ++tt) {
        int idx = u * 8 + tt;
        int h = idx % 9; int ij = idx / 9; int j = ij % 48; int i = ij / 48;
        const float* r1 = p1 + (h * 48 + i) * 48;
        const float4* r2 = (const float4*)(p2 + (h * 48 + j) * 48);
        f32x4* op = (f32x4*)(probs + (size_t)idx * SS);
        for (int g = t; g < 576; g += 256) {
            int k = g / 12, lq = g % 12;
            float s = r1[k];
            float4 q = r2[lq];
            f32x4 v; v[0] = s * q.x; v[1] = s * q.y; v[2] = s * q.z; v[3] = s * q.w;
            __builtin_nontemporal_store(v, op + g);
        }
    }
}

// ---------------------------------------------------------------------------
// K3 (tail): blocks 0..575 = gemmC, blocks 576.. = probs writer.  No LDS in
// either role -> both co-schedule at high occupancy (probs fills BW while
// gemmC blocks fetch).
// gemmC: out[b][e][m] = sum_k AF(k,m)*W(e,k) + vb[e].
//   block = (b, mb): M-tile 32, N = 256 (wave e0 = wave*64) -> AF fetched ONCE.
// ---------------------------------------------------------------------------
__global__ __launch_bounds__(256) void k_tail(const unsigned short* __restrict__ AF,
                                              const unsigned short* __restrict__ WF,
                                              const float* __restrict__ vb,
                                              float* __restrict__ out,
                                              const float* __restrict__ p1,
                                              const float* __restrict__ p2,
                                              float* __restrict__ probs) {
    int blk = blockIdx.x;
    int t = threadIdx.x;

    if (blk >= 576) {               // probs writer
        probs_unit(blk - 576, t, p1, p2, probs);
        return;
    }

    int b = blk / 72, mb = blk % 72;
    int lane = t & 63, wave = t >> 6;
    int l15 = lane & 15, quad = lane >> 4;
    int m0 = mb * 32;
    int e0 = wave * 64;

    const bf16x8* pa = (const bf16x8*)AF + (size_t)b * 288 * 2304
                       + (size_t)quad * 2304 + m0 + l15;
    const bf16x8* pw = (const bf16x8*)WF + (size_t)quad * 256 + e0 + l15;

    f32x4 acc[2][4];
    #pragma unroll
    for (int i = 0; i < 2; i++)
        #pragma unroll
        for (int j = 0; j < 4; j++) acc[i][j] = (f32x4){0.f, 0.f, 0.f, 0.f};

    bf16x8 a_cur[2], w_cur[4], a_nxt[2], w_nxt[4];
    a_cur[0] = pa[0];  a_cur[1] = pa[16];
    w_cur[0] = pw[0];  w_cur[1] = pw[16]; w_cur[2] = pw[32]; w_cur[3] = pw[48];

    for (int c = 0; c < 72; ++c) {
        if (c < 71) {
            a_nxt[0] = pa[9216];      a_nxt[1] = pa[9216 + 16];
            w_nxt[0] = pw[1024];      w_nxt[1] = pw[1024 + 16];
            w_nxt[2] = pw[1024 + 32]; w_nxt[3] = pw[1024 + 48];
        }
        #pragma unroll
        for (int tm = 0; tm < 2; ++tm)
            #pragma unroll
            for (int te = 0; te < 4; ++te)
                acc[tm][te] = __builtin_amdgcn_mfma_f32_16x16x32_bf16(
                    a_cur[tm], w_cur[te], acc[tm][te], 0, 0, 0);
        a_cur[0] = a_nxt[0]; a_cur[1] = a_nxt[1];
        w_cur[0] = w_nxt[0]; w_cur[1] = w_nxt[1]; w_cur[2] = w_nxt[2]; w_cur[3] = w_nxt[3];
        pa += 9216; pw += 1024;
    }

    size_t obase = (size_t)b * 589824;
    #pragma unroll
    for (int te = 0; te < 4; ++te) {
        int e = e0 + te * 16 + l15;
        float bias = vb[e];
        #pragma unroll
        for (int tm = 0; tm < 2; ++tm) {
            int m = m0 + tm * 16 + quad * 4;
            float4 v;
            v.x = acc[tm][te][0] + bias;
            v.y = acc[tm][te][1] + bias;
            v.z = acc[tm][te][2] + bias;
            v.w = acc[tm][te][3] + bias;
            *(float4*)(out + obase + (size_t)e * SS + m) = v;
        }
    }
}

// Separate probs kernel for the small-workspace fallback path
__global__ __launch_bounds__(256) void k_probs_sep(const float* __restrict__ p1,
                                                   const float* __restrict__ p2,
                                                   float* __restrict__ probs) {
    probs_unit(blockIdx.x, threadIdx.x, p1, p2, probs);
}

// ---------------------------------------------------------------------------
extern "C" void kernel_launch(void* const* d_in, const int* in_sizes, int n_in,
                              void* d_out, int out_size, void* d_ws, size_t ws_size,
                              hipStream_t stream) {
    const float* hs      = (const float*)d_in[0];
    const float* centers = (const float*)d_in[1];
    const float* spreads = (const float*)d_in[2];
    const float* Wv      = (const float*)d_in[3];
    const float* vbias   = (const float*)d_in[4];

    float* out   = (float*)d_out;
    float* probs = out + OUT0;                   // 47,775,744 floats (191 MB)

    const size_t needBig = 96000000;             // bytes (AF+WF+p1b/p2b+p1/p2+XB)
    bool big = ws_size >= needBig;

    unsigned short *AF, *WF, *p1b, *p2b, *XB;
    float *p1, *p2;
    if (big) {
        unsigned short* w = (unsigned short*)d_ws;
        AF  = w;                       // 42,467,328 bf16 (84.9 MB)
        WF  = AF + 42467328;           // 589,824 bf16
        p1b = WF + 589824;             // 27,648 bf16 each
        p2b = p1b + 27648;
        p1  = (float*)(p2b + 27648);   // 20,736 f32 each
        p2  = p1 + 20736;
        XB  = (unsigned short*)(p2 + 20736);  // 4,718,592 bf16 (9.4 MB)
    } else {
        p1  = (float*)d_ws;
        p2  = p1 + 20736;
        p1b = (unsigned short*)(p2 + 20736);
        p2b = p1b + 27648;
        AF  = (unsigned short*)probs;  // carve probs region; probs written last
        WF  = AF + 42467328;
        XB  = WF + 589824;             // still inside probs region (95.5 MB < 191 MB)
    }

    k_pre<<<1548, 256, 0, stream>>>(centers, spreads, hs, Wv, p1, p2, p1b, p2b, XB, WF);
    k_attn<<<2304, 256, 0, stream>>>(XB, p1b, p2b, AF);
    if (big) {
        k_tail<<<576 + 2592, 256, 0, stream>>>(AF, WF, vbias, out, p1, p2, probs);
    } else {
        k_tail<<<576, 256, 0, stream>>>(AF, WF, vbias, out, p1, p2, probs);
        k_probs_sep<<<2592, 256, 0, stream>>>(p1, p2, probs);
    }
}